// Round 5
// baseline (998.828 us; speedup 1.0000x reference)
//
#include <hip/hip_runtime.h>
#include <math.h>

#define T_LEN 1024
#define C_DIM 2048
#define H_N   32
#define HEAD  64
#define BTC   (T_LEN * C_DIM)
#define REC   384   // packed floats per (t,h): [d 64][a 64][b 64][k 64][v 64][r 64]

typedef __attribute__((ext_vector_type(8))) __bf16 bf16x8;
typedef __attribute__((ext_vector_type(4))) float  f32x4;

// ---------------- elementwise cast kernels ----------------
__global__ void cast_bf16_k(const float* __restrict__ s, __bf16* __restrict__ d, int n) {
    int i = blockIdx.x * 256 + threadIdx.x;
    if (i < n) d[i] = (__bf16)s[i];
}
__global__ void tanh_cast_k(const float* __restrict__ s, __bf16* __restrict__ d, int n) {
    int i = blockIdx.x * 256 + threadIdx.x;
    if (i < n) d[i] = (__bf16)tanhf(s[i]);
}

// ---------------- transpose + cast: dst[c*R + r] = (bf16)src[r*C + c] ----------------
__global__ void transpose_cast_k(const float* __restrict__ src, __bf16* __restrict__ dst,
                                 int R, int C) {
    __shared__ float tile[32][33];
    int c0 = blockIdx.x * 32, r0 = blockIdx.y * 32;
    int tx = threadIdx.x, ty = threadIdx.y;
#pragma unroll
    for (int i = 0; i < 32; i += 8)
        tile[ty + i][tx] = src[(size_t)(r0 + ty + i) * C + c0 + tx];
    __syncthreads();
#pragma unroll
    for (int i = 0; i < 32; i += 8)
        dst[(size_t)(c0 + ty + i) * R + r0 + tx] = (__bf16)tile[tx][ty + i];
}

// ---------------- big GEMM: O(MxN) fp32 = A(MxK) bf16 * BT(NxK) bf16 ----------------
__global__ __launch_bounds__(256) void gemm_bt_16x64(
    const __bf16* __restrict__ A, const __bf16* __restrict__ BT,
    float* __restrict__ O, int M, int N, int K) {
    int lane = threadIdx.x & 63;
    int wv   = threadIdx.x >> 6;
    int m    = lane & 15;
    int q    = lane >> 4;
    int row0 = blockIdx.x * 64 + wv * 16;
    int col0 = blockIdx.y * 64;

    const __bf16* ap = A  + (size_t)(row0 + m) * K + q * 8;
    const __bf16* bp = BT + (size_t)(col0 + m) * K + q * 8;
    size_t bstride = (size_t)16 * K;

    f32x4 acc0 = {0.f,0.f,0.f,0.f}, acc1 = acc0, acc2 = acc0, acc3 = acc0;

    for (int k0 = 0; k0 < K; k0 += 32) {
        bf16x8 av = *(const bf16x8*)(ap + k0);
        bf16x8 b0 = *(const bf16x8*)(bp + k0);
        bf16x8 b1 = *(const bf16x8*)(bp + bstride + k0);
        bf16x8 b2 = *(const bf16x8*)(bp + 2 * bstride + k0);
        bf16x8 b3 = *(const bf16x8*)(bp + 3 * bstride + k0);
        acc0 = __builtin_amdgcn_mfma_f32_16x16x32_bf16(av, b0, acc0, 0, 0, 0);
        acc1 = __builtin_amdgcn_mfma_f32_16x16x32_bf16(av, b1, acc1, 0, 0, 0);
        acc2 = __builtin_amdgcn_mfma_f32_16x16x32_bf16(av, b2, acc2, 0, 0, 0);
        acc3 = __builtin_amdgcn_mfma_f32_16x16x32_bf16(av, b3, acc3, 0, 0, 0);
    }
    int orow = row0 + q * 4;
    int ocol = col0 + m;
#pragma unroll
    for (int i = 0; i < 4; i++) {
        O[(size_t)(orow + i) * N + ocol]      = acc0[i];
        O[(size_t)(orow + i) * N + ocol + 16] = acc1[i];
        O[(size_t)(orow + i) * N + ocol + 32] = acc2[i];
        O[(size_t)(orow + i) * N + ocol + 48] = acc3[i];
    }
}

// ---------------- small GEMM: one wave per 16x16 tile ----------------
__global__ __launch_bounds__(64) void gemm_bt_w16(
    const __bf16* __restrict__ A, const __bf16* __restrict__ BT,
    float* __restrict__ O, int M, int N, int K) {
    int lane = threadIdx.x & 63;
    int m = lane & 15, q = lane >> 4;
    int row0 = blockIdx.x * 16;
    int col0 = blockIdx.y * 16;
    const __bf16* ap = A  + (size_t)(row0 + m) * K + q * 8;
    const __bf16* bp = BT + (size_t)(col0 + m) * K + q * 8;
    f32x4 acc = {0.f,0.f,0.f,0.f};
    for (int k0 = 0; k0 < K; k0 += 32) {
        bf16x8 av = *(const bf16x8*)(ap + k0);
        bf16x8 bv = *(const bf16x8*)(bp + k0);
        acc = __builtin_amdgcn_mfma_f32_16x16x32_bf16(av, bv, acc, 0, 0, 0);
    }
    int orow = row0 + q * 4;
    int ocol = col0 + m;
#pragma unroll
    for (int i = 0; i < 4; i++)
        O[(size_t)(orow + i) * N + ocol] = acc[i];
}

// ---------------- prep: decay / gates / kk-normalize + mask folding + packing ----------------
// Writes packed scan records pk[(t*H+h)*REC + {0:d,64:a,128:b,192:k,256:v,320:r}]
// and unmasked kbuf/vbuf for the residual.
__global__ __launch_bounds__(64) void prep_k(
    float* __restrict__ kbuf, float* __restrict__ vbuf,
    const float* __restrict__ vfirst, const float* __restrict__ rbuf,
    const float* __restrict__ ywb, const float* __restrict__ yab,
    const float* __restrict__ yvb,
    float* __restrict__ pk,
    const float* __restrict__ w0, const float* __restrict__ a0,
    const float* __restrict__ v0, const float* __restrict__ k_k,
    const float* __restrict__ k_a, const float* __restrict__ amask) {
    int t = blockIdx.x >> 5;
    int h = blockIdx.x & 31;
    int n = threadIdx.x;
    int cc  = h * HEAD + n;
    int idx = t * C_DIM + cc;
    float m = amask[t];

    float kv = kbuf[idx];
    float vv = vbuf[idx];
    float wv = w0[cc] + ywb[idx];
    float wfin = -log1pf(expf(-wv)) - 0.6f;       // -softplus(-x) - 0.6
    float dec  = expf(-expf(wfin));
    float sv   = 1.f / (1.f + expf(-(v0[cc] + yvb[idx])));
    float vnew = fmaf(vfirst[idx] - vv, sv, vv);
    float av   = 1.f / (1.f + expf(-(a0[cc] + yab[idx])));
    float kkp  = kv * k_k[cc];
    float ss = kkp * kkp;
#pragma unroll
    for (int off = 32; off > 0; off >>= 1) ss += __shfl_xor(ss, off);
    float kkn  = kkp / fmaxf(sqrtf(ss), 1e-12f);
    float knew = kv * (1.f + (av - 1.f) * k_a[cc]);

    size_t rec = ((size_t)t * H_N + h) * REC;
    pk[rec + n]       = dec * m + (1.f - m);   // d_eff
    pk[rec + 64 + n]  = -kkn * m;              // a_eff
    pk[rec + 128 + n] = kkn * av * m;          // b_eff
    pk[rec + 192 + n] = knew * m;              // k_eff
    pk[rec + 256 + n] = vnew * m;              // v_eff
    pk[rec + 320 + n] = rbuf[idx];             // r (unmasked)
    kbuf[idx] = knew;                          // unmasked, for residual
    vbuf[idx] = vnew;                          // unmasked, for residual
}

// ---------------- async global->LDS helper ----------------
__device__ __forceinline__ void gll16(const float* g, float* l) {
    __builtin_amdgcn_global_load_lds((const __attribute__((address_space(1))) void*)g,
                                     (__attribute__((address_space(3))) void*)l, 16, 0, 0);
}

// s_waitcnt immediates (gfx9: vmcnt[3:0]+[15:14], expcnt[6:4], lgkmcnt[11:8])
#define WAIT_VM6    3958   // vmcnt(6),  expcnt/lgkmcnt unconstrained
#define WAIT_LGKM0  49279  // lgkmcnt(0), vmcnt/expcnt unconstrained

// ---------------- sequential scan: 256 single-wave blocks, LDS-DMA ring-4 pipeline ----------------
// block = (head h, row-group g); lane = (r<<3)|c holds S[g*8+r][c*8..c*8+8).
// XCD swizzle: 8 row-groups of a head share blockIdx%8 -> same XCD L2.
// Per step: exactly 2 DMA issues + 1 store in the vmem queue; vmcnt(6) retires
// the slot being consumed while keeping ~3 steps of prefetch in flight.
__global__ __launch_bounds__(64) void scan_k(
    const float* __restrict__ pk, float* __restrict__ out) {
    int b = blockIdx.x;
    int xcd  = b & 7;
    int rest = b >> 3;
    int hi   = rest & 3;
    int g    = rest >> 2;
    int h    = xcd + 8 * hi;

    int lane = threadIdx.x;
    int r = lane >> 3;
    int c = lane & 7;
    int row = g * 8 + r;
    int jb  = c * 8;

    __shared__ float lds[4][512];   // slot: [d|a|b|k|v|r|pad128]

    float S[8];
#pragma unroll
    for (int j = 0; j < 8; j++) S[j] = 0.f;

    auto issue_slot = [&](int slot, int t) {
        const float* rec = pk + ((size_t)t * H_N + h) * REC;
        gll16(rec + lane * 4, &lds[slot][0]);          // floats [0,256): d,a,b,k
        gll16(rec + 256 + lane * 4, &lds[slot][256]);  // floats [256,512): v,r (+128 overread)
    };

    // prologue: fill ring (8 DMAs outstanding)
    issue_slot(0, 0);
    issue_slot(1, 1);
    issue_slot(2, 2);
    issue_slot(3, 3);

    int off = h * HEAD;

    for (int t = 0; t < T_LEN; t++) {
        int slot = t & 3;
        __builtin_amdgcn_s_waitcnt(WAIT_VM6);    // slot's 2 DMAs retired
        const float* L = &lds[slot][0];
        float dv[8], av[8], bv[8], kv[8], rv[8];
        *(float4*)&dv[0] = *(const float4*)(L + jb);
        *(float4*)&dv[4] = *(const float4*)(L + jb + 4);
        *(float4*)&av[0] = *(const float4*)(L + 64 + jb);
        *(float4*)&av[4] = *(const float4*)(L + 64 + jb + 4);
        *(float4*)&bv[0] = *(const float4*)(L + 128 + jb);
        *(float4*)&bv[4] = *(const float4*)(L + 128 + jb + 4);
        *(float4*)&kv[0] = *(const float4*)(L + 192 + jb);
        *(float4*)&kv[4] = *(const float4*)(L + 192 + jb + 4);
        float vv = L[256 + row];
        *(float4*)&rv[0] = *(const float4*)(L + 320 + jb);
        *(float4*)&rv[4] = *(const float4*)(L + 320 + jb + 4);

        // all operands in registers -> slot reusable
        __builtin_amdgcn_s_waitcnt(WAIT_LGKM0);
        int tn = (t + 4 < T_LEN) ? t + 4 : T_LEN - 1;
        issue_slot(slot, tn);

        // sa = sum_j S[j]*a[j], reduced over the 8 col-chunks
        float p0 = 0.f, p1 = 0.f;
#pragma unroll
        for (int j = 0; j < 4; j++) {
            p0 = fmaf(S[j],     av[j],     p0);
            p1 = fmaf(S[j + 4], av[j + 4], p1);
        }
        float p = p0 + p1;
        p += __shfl_xor(p, 1);
        p += __shfl_xor(p, 2);
        p += __shfl_xor(p, 4);
        float sa = p;

        // state update + output dot
        float o0 = 0.f, o1 = 0.f;
#pragma unroll
        for (int j = 0; j < 4; j++) {
            float s0 = fmaf(dv[j], S[j], fmaf(sa, bv[j], vv * kv[j]));
            S[j] = s0;
            o0 = fmaf(s0, rv[j], o0);
            float s1 = fmaf(dv[j + 4], S[j + 4], fmaf(sa, bv[j + 4], vv * kv[j + 4]));
            S[j + 4] = s1;
            o1 = fmaf(s1, rv[j + 4], o1);
        }
        float op = o0 + o1;
        op += __shfl_xor(op, 1);
        op += __shfl_xor(op, 2);
        op += __shfl_xor(op, 4);
        if (c == 0) out[off + row] = op;

        off += C_DIM;
    }
}

// ---------------- residual + cast + v_first passthrough ----------------
__global__ __launch_bounds__(64) void resid_k(
    const float* __restrict__ rbuf, const float* __restrict__ kbuf,
    const float* __restrict__ vbuf, const float* __restrict__ souts,
    const float* __restrict__ r_k, const float* __restrict__ vfirst,
    __bf16* __restrict__ ob, float* __restrict__ dout) {
    int t = blockIdx.x >> 5;
    int h = blockIdx.x & 31;
    int n = threadIdx.x;
    int idx = t * C_DIM + h * HEAD + n;
    float s = rbuf[idx] * kbuf[idx] * r_k[h * HEAD + n];
#pragma unroll
    for (int off = 32; off > 0; off >>= 1) s += __shfl_xor(s, off);
    float ov = souts[idx] + s * vbuf[idx];
    ob[idx] = (__bf16)ov;
    dout[BTC + idx] = vfirst[idx];
}

// ---------------- host launcher ----------------
extern "C" void kernel_launch(void* const* d_in, const int* in_sizes, int n_in,
                              void* d_out, int out_size, void* d_ws, size_t ws_size,
                              hipStream_t stream) {
    const float* x      = (const float*)d_in[0];
    const float* vfirst = (const float*)d_in[1];
    const float* amask  = (const float*)d_in[2];
    const float* w0 = (const float*)d_in[3];
    const float* w1 = (const float*)d_in[4];
    const float* w2 = (const float*)d_in[5];
    const float* a0 = (const float*)d_in[6];
    const float* a1 = (const float*)d_in[7];
    const float* a2 = (const float*)d_in[8];
    const float* v0 = (const float*)d_in[9];
    const float* v1 = (const float*)d_in[10];
    const float* v2 = (const float*)d_in[11];
    const float* k_k = (const float*)d_in[12];
    const float* k_a = (const float*)d_in[13];
    const float* r_k = (const float*)d_in[14];
    const float* Wr = (const float*)d_in[15];
    const float* Wk = (const float*)d_in[16];
    const float* Wv = (const float*)d_in[17];
    const float* Wo = (const float*)d_in[18];
    float* dout = (float*)d_out;

    char* wp = (char*)d_ws;
    auto alloc = [&](size_t bytes) -> void* {
        void* p = (void*)wp;
        wp += (bytes + 255) & ~(size_t)255;
        return p;
    };
    __bf16* xb  = (__bf16*)alloc((size_t)BTC * 2);
    __bf16* WrT = (__bf16*)alloc((size_t)C_DIM * C_DIM * 2);
    __bf16* WkT = (__bf16*)alloc((size_t)C_DIM * C_DIM * 2);
    __bf16* WvT = (__bf16*)alloc((size_t)C_DIM * C_DIM * 2);
    __bf16* WoT = (__bf16*)alloc((size_t)C_DIM * C_DIM * 2);
    __bf16* w1T = (__bf16*)alloc((size_t)96 * C_DIM * 2);
    __bf16* a1T = (__bf16*)alloc((size_t)96 * C_DIM * 2);
    __bf16* v1T = (__bf16*)alloc((size_t)64 * C_DIM * 2);
    __bf16* w2T = (__bf16*)alloc((size_t)C_DIM * 96 * 2);
    __bf16* a2T = (__bf16*)alloc((size_t)C_DIM * 96 * 2);
    __bf16* v2T = (__bf16*)alloc((size_t)C_DIM * 64 * 2);
    float*  rbuf = (float*)alloc((size_t)BTC * 4);
    float*  kbuf = (float*)alloc((size_t)BTC * 4);
    float*  vbuf = (float*)alloc((size_t)BTC * 4);
    float*  hw  = (float*)alloc((size_t)T_LEN * 96 * 4);
    float*  ha  = (float*)alloc((size_t)T_LEN * 96 * 4);
    float*  hv  = (float*)alloc((size_t)T_LEN * 64 * 4);
    __bf16* hwb = (__bf16*)alloc((size_t)T_LEN * 96 * 2);
    __bf16* hab = (__bf16*)alloc((size_t)T_LEN * 96 * 2);
    __bf16* hvb = (__bf16*)alloc((size_t)T_LEN * 64 * 2);
    float*  ywb = (float*)alloc((size_t)BTC * 4);   // LoRA w output
    float*  yab = (float*)alloc((size_t)BTC * 4);   // LoRA a output
    float*  yvb = (float*)alloc((size_t)BTC * 4);   // LoRA v output
    float*  pk  = (float*)alloc((size_t)T_LEN * H_N * REC * 4 + 4096);  // packed records + DMA overread pad
    float*  souts = (float*)alloc((size_t)BTC * 4);
    __bf16* ob  = (__bf16*)alloc((size_t)BTC * 2);

    // 1) cast x -> bf16
    cast_bf16_k<<<dim3(BTC / 256), 256, 0, stream>>>(x, xb, BTC);

    // 2) transpose+cast all weights (dst = C x R)
    dim3 tb(32, 8);
    transpose_cast_k<<<dim3(64, 64), tb, 0, stream>>>(Wr, WrT, C_DIM, C_DIM);
    transpose_cast_k<<<dim3(64, 64), tb, 0, stream>>>(Wk, WkT, C_DIM, C_DIM);
    transpose_cast_k<<<dim3(64, 64), tb, 0, stream>>>(Wv, WvT, C_DIM, C_DIM);
    transpose_cast_k<<<dim3(64, 64), tb, 0, stream>>>(Wo, WoT, C_DIM, C_DIM);
    transpose_cast_k<<<dim3(3, 64), tb, 0, stream>>>(w1, w1T, C_DIM, 96);
    transpose_cast_k<<<dim3(3, 64), tb, 0, stream>>>(a1, a1T, C_DIM, 96);
    transpose_cast_k<<<dim3(2, 64), tb, 0, stream>>>(v1, v1T, C_DIM, 64);
    transpose_cast_k<<<dim3(64, 3), tb, 0, stream>>>(w2, w2T, 96, C_DIM);
    transpose_cast_k<<<dim3(64, 3), tb, 0, stream>>>(a2, a2T, 96, C_DIM);
    transpose_cast_k<<<dim3(64, 2), tb, 0, stream>>>(v2, v2T, 64, C_DIM);

    // 3) big GEMMs: r, k, v
    gemm_bt_16x64<<<dim3(16, 32), 256, 0, stream>>>(xb, WrT, rbuf, T_LEN, C_DIM, C_DIM);
    gemm_bt_16x64<<<dim3(16, 32), 256, 0, stream>>>(xb, WkT, kbuf, T_LEN, C_DIM, C_DIM);
    gemm_bt_16x64<<<dim3(16, 32), 256, 0, stream>>>(xb, WvT, vbuf, T_LEN, C_DIM, C_DIM);

    // 4) LoRA first stage
    gemm_bt_w16<<<dim3(64, 6), 64, 0, stream>>>(xb, w1T, hw, T_LEN, 96, C_DIM);
    gemm_bt_w16<<<dim3(64, 6), 64, 0, stream>>>(xb, a1T, ha, T_LEN, 96, C_DIM);
    gemm_bt_w16<<<dim3(64, 4), 64, 0, stream>>>(xb, v1T, hv, T_LEN, 64, C_DIM);

    // 5) activations + cast
    tanh_cast_k<<<dim3((T_LEN * 96 + 255) / 256), 256, 0, stream>>>(hw, hwb, T_LEN * 96);
    cast_bf16_k<<<dim3((T_LEN * 96 + 255) / 256), 256, 0, stream>>>(ha, hab, T_LEN * 96);
    cast_bf16_k<<<dim3((T_LEN * 64 + 255) / 256), 256, 0, stream>>>(hv, hvb, T_LEN * 64);

    // 6) LoRA second stage
    gemm_bt_w16<<<dim3(64, 128), 64, 0, stream>>>(hwb, w2T, ywb, T_LEN, C_DIM, 96);
    gemm_bt_w16<<<dim3(64, 128), 64, 0, stream>>>(hab, a2T, yab, T_LEN, C_DIM, 96);
    gemm_bt_w16<<<dim3(64, 128), 64, 0, stream>>>(hvb, v2T, yvb, T_LEN, C_DIM, 64);

    // 7) prep: decay, gates, kk-normalize, mask folding, record packing
    prep_k<<<dim3(T_LEN * H_N), 64, 0, stream>>>(kbuf, vbuf, vfirst, rbuf, ywb, yab, yvb,
                                                 pk, w0, a0, v0, k_k, k_a, amask);

    // 8) sequential scan: 256 blocks x 1 wave, LDS-DMA ring-4 pipeline, XCD swizzle
    scan_k<<<dim3(H_N * 8), 64, 0, stream>>>(pk, souts);

    // 9) residual + cast + v_first passthrough
    resid_k<<<dim3(T_LEN * H_N), 64, 0, stream>>>(rbuf, kbuf, vbuf, souts, r_k, vfirst,
                                                  ob, dout);

    // 10) final GEMM: dout[0:BTC] = ob @ Wo
    gemm_bt_16x64<<<dim3(16, 32), 256, 0, stream>>>(ob, WoT, dout, T_LEN, C_DIM, C_DIM);
}

// Round 6
// 955.639 us; speedup vs baseline: 1.0452x; 1.0452x over previous
//
#include <hip/hip_runtime.h>
#include <math.h>

#define T_LEN 1024
#define C_DIM 2048
#define H_N   32
#define HEAD  64
#define BTC   (T_LEN * C_DIM)
#define REC   384   // packed floats per (t,h): [d 64][a 64][b 64][k 64][v 64][r 64]

typedef __attribute__((ext_vector_type(8))) __bf16 bf16x8;
typedef __attribute__((ext_vector_type(4))) float  f32x4;

// s_waitcnt immediates (gfx9: vmcnt[3:0]+[15:14], expcnt[6:4], lgkmcnt[11:8])
#define WAIT_VM6    3958   // vmcnt(6),  expcnt/lgkmcnt unconstrained
#define WAIT_LGKM0  49279  // lgkmcnt(0), vmcnt/expcnt unconstrained

// ---------------- async global->LDS helper (16B/lane, wave-uniform LDS base) -------------
__device__ __forceinline__ void gll16(const void* g, void* l) {
    __builtin_amdgcn_global_load_lds((const __attribute__((address_space(1))) void*)g,
                                     (__attribute__((address_space(3))) void*)l, 16, 0, 0);
}

// quad reduction via DPP (VALU latency, no LDS pipe)
__device__ __forceinline__ float quad_add(float x) {
    int a = __builtin_amdgcn_mov_dpp(__float_as_int(x), 0xB1, 0xF, 0xF, true); // quad_perm xor1
    float y = x + __int_as_float(a);
    int b = __builtin_amdgcn_mov_dpp(__float_as_int(y), 0x4E, 0xF, 0xF, true); // quad_perm xor2
    return y + __int_as_float(b);
}

// ---------------- elementwise cast kernels ----------------
__global__ void cast_bf16_k(const float* __restrict__ s, __bf16* __restrict__ d, int n) {
    int i = blockIdx.x * 256 + threadIdx.x;
    if (i < n) d[i] = (__bf16)s[i];
}
__global__ void tanh_cast_k(const float* __restrict__ s, __bf16* __restrict__ d, int n) {
    int i = blockIdx.x * 256 + threadIdx.x;
    if (i < n) d[i] = (__bf16)tanhf(s[i]);
}

// ---------------- transpose + cast: dst[c*R + r] = (bf16)src[r*C + c] ----------------
__global__ void transpose_cast_k(const float* __restrict__ src, __bf16* __restrict__ dst,
                                 int R, int C) {
    __shared__ float tile[32][33];
    int c0 = blockIdx.x * 32, r0 = blockIdx.y * 32;
    int tx = threadIdx.x, ty = threadIdx.y;
#pragma unroll
    for (int i = 0; i < 32; i += 8)
        tile[ty + i][tx] = src[(size_t)(r0 + ty + i) * C + c0 + tx];
    __syncthreads();
#pragma unroll
    for (int i = 0; i < 32; i += 8)
        dst[(size_t)(c0 + ty + i) * R + r0 + tx] = (__bf16)tile[tx][ty + i];
}

// ---------------- big GEMM, m97 structure: 128x128 tile, LDS-DMA staging ----------------
// O(MxN) fp32 = A(MxK) bf16 * BT(NxK) bf16. block 256 = 4 waves (2x2 quadrants of 64x64),
// wave does 4x4 16x16 tiles -> 16 MFMA : 8 ds_read_b128 per K-iter.
__global__ __launch_bounds__(256) void gemm_lds_128(
    const __bf16* __restrict__ A, const __bf16* __restrict__ BT,
    float* __restrict__ O, int M, int N, int K) {
    __shared__ __bf16 As[128 * 32];
    __shared__ __bf16 Bs[128 * 32];
    int tid  = threadIdx.x;
    int lane = tid & 63;
    int wv   = tid >> 6;
    int m    = lane & 15;
    int q    = lane >> 4;
    int wr   = wv >> 1, wc = wv & 1;
    int row0 = blockIdx.x * 128;
    int col0 = blockIdx.y * 128;

    // staging: thread i covers row i>>2 (and +64), k-offset (i&3)*8, 16B each
    int srow  = tid >> 2;
    int skoff = (tid & 3) * 8;
    const __bf16* agp = A  + (size_t)(row0 + srow) * K + skoff;
    const __bf16* bgp = BT + (size_t)(col0 + srow) * K + skoff;
    __bf16* alp = As + (size_t)(tid & ~63) * 8;   // wave-uniform base (+ HW lane*16B)
    __bf16* blp = Bs + (size_t)(tid & ~63) * 8;

    f32x4 acc[4][4];
#pragma unroll
    for (int i = 0; i < 4; i++)
#pragma unroll
        for (int j = 0; j < 4; j++) acc[i][j] = {0.f, 0.f, 0.f, 0.f};

    for (int k0 = 0; k0 < K; k0 += 32) {
        gll16(agp + k0, alp);
        gll16(agp + (size_t)64 * K + k0, alp + 64 * 32);
        gll16(bgp + k0, blp);
        gll16(bgp + (size_t)64 * K + k0, blp + 64 * 32);
        __syncthreads();   // emits full vmcnt drain -> DMA complete

        bf16x8 af[4], bf[4];
#pragma unroll
        for (int i = 0; i < 4; i++)
            af[i] = *(const bf16x8*)&As[(wr * 64 + i * 16 + m) * 32 + q * 8];
#pragma unroll
        for (int j = 0; j < 4; j++)
            bf[j] = *(const bf16x8*)&Bs[(wc * 64 + j * 16 + m) * 32 + q * 8];
#pragma unroll
        for (int i = 0; i < 4; i++)
#pragma unroll
            for (int j = 0; j < 4; j++)
                acc[i][j] = __builtin_amdgcn_mfma_f32_16x16x32_bf16(af[i], bf[j], acc[i][j], 0, 0, 0);
        __syncthreads();
    }

#pragma unroll
    for (int i = 0; i < 4; i++) {
        int orow = row0 + wr * 64 + i * 16 + q * 4;
#pragma unroll
        for (int j = 0; j < 4; j++) {
            int ocol = col0 + wc * 64 + j * 16 + m;
#pragma unroll
            for (int t = 0; t < 4; t++)
                O[(size_t)(orow + t) * N + ocol] = acc[i][j][t];
        }
    }
}

// ---------------- small GEMM: one wave per 16x16 tile ----------------
__global__ __launch_bounds__(64) void gemm_bt_w16(
    const __bf16* __restrict__ A, const __bf16* __restrict__ BT,
    float* __restrict__ O, int M, int N, int K) {
    int lane = threadIdx.x & 63;
    int m = lane & 15, q = lane >> 4;
    int row0 = blockIdx.x * 16;
    int col0 = blockIdx.y * 16;
    const __bf16* ap = A  + (size_t)(row0 + m) * K + q * 8;
    const __bf16* bp = BT + (size_t)(col0 + m) * K + q * 8;
    f32x4 acc = {0.f,0.f,0.f,0.f};
    for (int k0 = 0; k0 < K; k0 += 32) {
        bf16x8 av = *(const bf16x8*)(ap + k0);
        bf16x8 bv = *(const bf16x8*)(bp + k0);
        acc = __builtin_amdgcn_mfma_f32_16x16x32_bf16(av, bv, acc, 0, 0, 0);
    }
    int orow = row0 + q * 4;
    int ocol = col0 + m;
#pragma unroll
    for (int i = 0; i < 4; i++)
        O[(size_t)(orow + i) * N + ocol] = acc[i];
}

// ---------------- prep: decay / gates / kk-normalize + mask folding + packing ----------------
__global__ __launch_bounds__(64) void prep_k(
    float* __restrict__ kbuf, float* __restrict__ vbuf,
    const float* __restrict__ vfirst, const float* __restrict__ rbuf,
    const float* __restrict__ ywb, const float* __restrict__ yab,
    const float* __restrict__ yvb,
    float* __restrict__ pk,
    const float* __restrict__ w0, const float* __restrict__ a0,
    const float* __restrict__ v0, const float* __restrict__ k_k,
    const float* __restrict__ k_a, const float* __restrict__ amask) {
    int t = blockIdx.x >> 5;
    int h = blockIdx.x & 31;
    int n = threadIdx.x;
    int cc  = h * HEAD + n;
    int idx = t * C_DIM + cc;
    float m = amask[t];

    float kv = kbuf[idx];
    float vv = vbuf[idx];
    float wv = w0[cc] + ywb[idx];
    float wfin = -log1pf(expf(-wv)) - 0.6f;       // -softplus(-x) - 0.6
    float dec  = expf(-expf(wfin));
    float sv   = 1.f / (1.f + expf(-(v0[cc] + yvb[idx])));
    float vnew = fmaf(vfirst[idx] - vv, sv, vv);
    float av   = 1.f / (1.f + expf(-(a0[cc] + yab[idx])));
    float kkp  = kv * k_k[cc];
    float ss = kkp * kkp;
#pragma unroll
    for (int off = 32; off > 0; off >>= 1) ss += __shfl_xor(ss, off);
    float kkn  = kkp / fmaxf(sqrtf(ss), 1e-12f);
    float knew = kv * (1.f + (av - 1.f) * k_a[cc]);

    size_t rec = ((size_t)t * H_N + h) * REC;
    pk[rec + n]       = dec * m + (1.f - m);   // d_eff
    pk[rec + 64 + n]  = -kkn * m;              // a_eff
    pk[rec + 128 + n] = kkn * av * m;          // b_eff
    pk[rec + 192 + n] = knew * m;              // k_eff
    pk[rec + 256 + n] = vnew * m;              // v_eff
    pk[rec + 320 + n] = rbuf[idx];             // r (unmasked)
    kbuf[idx] = knew;                          // unmasked, for residual
    vbuf[idx] = vnew;                          // unmasked, for residual
}

// ---------------- sequential scan: 128 single-wave blocks, DPP reduce, LDS-DMA ring-4 ----
// block = (head h, row-quarter g of 16 rows); lane = r*4+q: holds S[g*16+r][q*16..q*16+16).
// Quad lanes (same r) reduce via quad_perm DPP — no ds_swizzle latency on the chain.
// Per step: 2 DMA + 1 store in vmem queue; vmcnt(6) retires the consumed slot.
__global__ __launch_bounds__(64) void scan_k(
    const float* __restrict__ pk, float* __restrict__ out) {
    int b = blockIdx.x;
    int xcd  = b & 7;
    int rest = b >> 3;
    int hi   = rest & 3;
    int g    = rest >> 2;          // 0..3
    int h    = xcd + 8 * hi;

    int lane = threadIdx.x;
    int r = lane >> 2;             // 0..15
    int q = lane & 3;              // 0..3
    int row = g * 16 + r;
    int jb  = q * 16;

    __shared__ float lds[4][512];  // slot: [d|a|b|k|v|r|pad128]

    float S[16];
#pragma unroll
    for (int j = 0; j < 16; j++) S[j] = 0.f;

    auto issue_slot = [&](int slot, int t) {
        const float* rec = pk + ((size_t)t * H_N + h) * REC;
        gll16(rec + lane * 4, &lds[slot][0]);          // floats [0,256): d,a,b,k
        gll16(rec + 256 + lane * 4, &lds[slot][256]);  // floats [256,512): v,r (+overread)
    };

    issue_slot(0, 0);
    issue_slot(1, 1);
    issue_slot(2, 2);
    issue_slot(3, 3);

    int off = h * HEAD;

    for (int t = 0; t < T_LEN; t++) {
        int slot = t & 3;
        __builtin_amdgcn_s_waitcnt(WAIT_VM6);    // slot's 2 DMAs retired
        const float* L = &lds[slot][0];
        float dv[16], av[16], bv[16], kv[16], rv[16];
#pragma unroll
        for (int u = 0; u < 4; u++) {
            *(float4*)&av[u * 4] = *(const float4*)(L + 64  + jb + u * 4);
            *(float4*)&dv[u * 4] = *(const float4*)(L +       jb + u * 4);
            *(float4*)&bv[u * 4] = *(const float4*)(L + 128 + jb + u * 4);
            *(float4*)&kv[u * 4] = *(const float4*)(L + 192 + jb + u * 4);
            *(float4*)&rv[u * 4] = *(const float4*)(L + 320 + jb + u * 4);
        }
        float vv = L[256 + row];

        // all operands in registers -> slot reusable
        __builtin_amdgcn_s_waitcnt(WAIT_LGKM0);
        int tn = (t + 4 < T_LEN) ? t + 4 : T_LEN - 1;
        issue_slot(slot, tn);

        // sa = sum_j S[j]*a[j] over the row (16 local + quad reduce via DPP)
        float p0 = 0.f, p1 = 0.f, p2 = 0.f, p3 = 0.f;
#pragma unroll
        for (int j = 0; j < 4; j++) {
            p0 = fmaf(S[j],      av[j],      p0);
            p1 = fmaf(S[j + 4],  av[j + 4],  p1);
            p2 = fmaf(S[j + 8],  av[j + 8],  p2);
            p3 = fmaf(S[j + 12], av[j + 12], p3);
        }
        float sa = quad_add((p0 + p1) + (p2 + p3));

        // state update + output dot
        float o0 = 0.f, o1 = 0.f, o2 = 0.f, o3 = 0.f;
#pragma unroll
        for (int j = 0; j < 4; j++) {
            float s0 = fmaf(dv[j], S[j], fmaf(sa, bv[j], vv * kv[j]));
            S[j] = s0;  o0 = fmaf(s0, rv[j], o0);
            float s1 = fmaf(dv[j + 4], S[j + 4], fmaf(sa, bv[j + 4], vv * kv[j + 4]));
            S[j + 4] = s1;  o1 = fmaf(s1, rv[j + 4], o1);
            float s2 = fmaf(dv[j + 8], S[j + 8], fmaf(sa, bv[j + 8], vv * kv[j + 8]));
            S[j + 8] = s2;  o2 = fmaf(s2, rv[j + 8], o2);
            float s3 = fmaf(dv[j + 12], S[j + 12], fmaf(sa, bv[j + 12], vv * kv[j + 12]));
            S[j + 12] = s3;  o3 = fmaf(s3, rv[j + 12], o3);
        }
        float op = quad_add((o0 + o1) + (o2 + o3));
        if (q == 0) out[off + row] = op;

        off += C_DIM;
    }
}

// ---------------- residual + cast + v_first passthrough ----------------
__global__ __launch_bounds__(64) void resid_k(
    const float* __restrict__ rbuf, const float* __restrict__ kbuf,
    const float* __restrict__ vbuf, const float* __restrict__ souts,
    const float* __restrict__ r_k, const float* __restrict__ vfirst,
    __bf16* __restrict__ ob, float* __restrict__ dout) {
    int t = blockIdx.x >> 5;
    int h = blockIdx.x & 31;
    int n = threadIdx.x;
    int idx = t * C_DIM + h * HEAD + n;
    float s = rbuf[idx] * kbuf[idx] * r_k[h * HEAD + n];
#pragma unroll
    for (int off = 32; off > 0; off >>= 1) s += __shfl_xor(s, off);
    float ov = souts[idx] + s * vbuf[idx];
    ob[idx] = (__bf16)ov;
    dout[BTC + idx] = vfirst[idx];
}

// ---------------- host launcher ----------------
extern "C" void kernel_launch(void* const* d_in, const int* in_sizes, int n_in,
                              void* d_out, int out_size, void* d_ws, size_t ws_size,
                              hipStream_t stream) {
    const float* x      = (const float*)d_in[0];
    const float* vfirst = (const float*)d_in[1];
    const float* amask  = (const float*)d_in[2];
    const float* w0 = (const float*)d_in[3];
    const float* w1 = (const float*)d_in[4];
    const float* w2 = (const float*)d_in[5];
    const float* a0 = (const float*)d_in[6];
    const float* a1 = (const float*)d_in[7];
    const float* a2 = (const float*)d_in[8];
    const float* v0 = (const float*)d_in[9];
    const float* v1 = (const float*)d_in[10];
    const float* v2 = (const float*)d_in[11];
    const float* k_k = (const float*)d_in[12];
    const float* k_a = (const float*)d_in[13];
    const float* r_k = (const float*)d_in[14];
    const float* Wr = (const float*)d_in[15];
    const float* Wk = (const float*)d_in[16];
    const float* Wv = (const float*)d_in[17];
    const float* Wo = (const float*)d_in[18];
    float* dout = (float*)d_out;

    char* wp = (char*)d_ws;
    auto alloc = [&](size_t bytes) -> void* {
        void* p = (void*)wp;
        wp += (bytes + 255) & ~(size_t)255;
        return p;
    };
    __bf16* xb  = (__bf16*)alloc((size_t)BTC * 2);
    __bf16* WrT = (__bf16*)alloc((size_t)C_DIM * C_DIM * 2);
    __bf16* WkT = (__bf16*)alloc((size_t)C_DIM * C_DIM * 2);
    __bf16* WvT = (__bf16*)alloc((size_t)C_DIM * C_DIM * 2);
    __bf16* WoT = (__bf16*)alloc((size_t)C_DIM * C_DIM * 2);
    __bf16* w1T = (__bf16*)alloc((size_t)96 * C_DIM * 2);
    __bf16* a1T = (__bf16*)alloc((size_t)96 * C_DIM * 2);
    __bf16* v1T = (__bf16*)alloc((size_t)64 * C_DIM * 2);
    __bf16* w2T = (__bf16*)alloc((size_t)C_DIM * 96 * 2);
    __bf16* a2T = (__bf16*)alloc((size_t)C_DIM * 96 * 2);
    __bf16* v2T = (__bf16*)alloc((size_t)C_DIM * 64 * 2);
    float*  rbuf = (float*)alloc((size_t)BTC * 4);
    float*  kbuf = (float*)alloc((size_t)BTC * 4);
    float*  vbuf = (float*)alloc((size_t)BTC * 4);
    float*  hw  = (float*)alloc((size_t)T_LEN * 96 * 4);
    float*  ha  = (float*)alloc((size_t)T_LEN * 96 * 4);
    float*  hv  = (float*)alloc((size_t)T_LEN * 64 * 4);
    __bf16* hwb = (__bf16*)alloc((size_t)T_LEN * 96 * 2);
    __bf16* hab = (__bf16*)alloc((size_t)T_LEN * 96 * 2);
    __bf16* hvb = (__bf16*)alloc((size_t)T_LEN * 64 * 2);
    float*  ywb = (float*)alloc((size_t)BTC * 4);   // LoRA w output
    float*  yab = (float*)alloc((size_t)BTC * 4);   // LoRA a output
    float*  yvb = (float*)alloc((size_t)BTC * 4);   // LoRA v output
    float*  pk  = (float*)alloc((size_t)T_LEN * H_N * REC * 4 + 4096);
    float*  souts = (float*)alloc((size_t)BTC * 4);
    __bf16* ob  = (__bf16*)alloc((size_t)BTC * 2);

    // 1) cast x -> bf16
    cast_bf16_k<<<dim3(BTC / 256), 256, 0, stream>>>(x, xb, BTC);

    // 2) transpose+cast all weights (dst = C x R)
    dim3 tb(32, 8);
    transpose_cast_k<<<dim3(64, 64), tb, 0, stream>>>(Wr, WrT, C_DIM, C_DIM);
    transpose_cast_k<<<dim3(64, 64), tb, 0, stream>>>(Wk, WkT, C_DIM, C_DIM);
    transpose_cast_k<<<dim3(64, 64), tb, 0, stream>>>(Wv, WvT, C_DIM, C_DIM);
    transpose_cast_k<<<dim3(64, 64), tb, 0, stream>>>(Wo, WoT, C_DIM, C_DIM);
    transpose_cast_k<<<dim3(3, 64), tb, 0, stream>>>(w1, w1T, C_DIM, 96);
    transpose_cast_k<<<dim3(3, 64), tb, 0, stream>>>(a1, a1T, C_DIM, 96);
    transpose_cast_k<<<dim3(2, 64), tb, 0, stream>>>(v1, v1T, C_DIM, 64);
    transpose_cast_k<<<dim3(64, 3), tb, 0, stream>>>(w2, w2T, 96, C_DIM);
    transpose_cast_k<<<dim3(64, 3), tb, 0, stream>>>(a2, a2T, 96, C_DIM);
    transpose_cast_k<<<dim3(64, 2), tb, 0, stream>>>(v2, v2T, 64, C_DIM);

    // 3) big GEMMs: r, k, v (m97-style LDS-staged)
    gemm_lds_128<<<dim3(8, 16), 256, 0, stream>>>(xb, WrT, rbuf, T_LEN, C_DIM, C_DIM);
    gemm_lds_128<<<dim3(8, 16), 256, 0, stream>>>(xb, WkT, kbuf, T_LEN, C_DIM, C_DIM);
    gemm_lds_128<<<dim3(8, 16), 256, 0, stream>>>(xb, WvT, vbuf, T_LEN, C_DIM, C_DIM);

    // 4) LoRA first stage
    gemm_bt_w16<<<dim3(64, 6), 64, 0, stream>>>(xb, w1T, hw, T_LEN, 96, C_DIM);
    gemm_bt_w16<<<dim3(64, 6), 64, 0, stream>>>(xb, a1T, ha, T_LEN, 96, C_DIM);
    gemm_bt_w16<<<dim3(64, 4), 64, 0, stream>>>(xb, v1T, hv, T_LEN, 64, C_DIM);

    // 5) activations + cast
    tanh_cast_k<<<dim3((T_LEN * 96 + 255) / 256), 256, 0, stream>>>(hw, hwb, T_LEN * 96);
    cast_bf16_k<<<dim3((T_LEN * 96 + 255) / 256), 256, 0, stream>>>(ha, hab, T_LEN * 96);
    cast_bf16_k<<<dim3((T_LEN * 64 + 255) / 256), 256, 0, stream>>>(hv, hvb, T_LEN * 64);

    // 6) LoRA second stage
    gemm_bt_w16<<<dim3(64, 128), 64, 0, stream>>>(hwb, w2T, ywb, T_LEN, C_DIM, 96);
    gemm_bt_w16<<<dim3(64, 128), 64, 0, stream>>>(hab, a2T, yab, T_LEN, C_DIM, 96);
    gemm_bt_w16<<<dim3(64, 128), 64, 0, stream>>>(hvb, v2T, yvb, T_LEN, C_DIM, 64);

    // 7) prep: decay, gates, kk-normalize, mask folding, record packing
    prep_k<<<dim3(T_LEN * H_N), 64, 0, stream>>>(kbuf, vbuf, vfirst, rbuf, ywb, yab, yvb,
                                                 pk, w0, a0, v0, k_k, k_a, amask);

    // 8) sequential scan: 128 blocks x 1 wave, DPP quad-reduce, LDS-DMA ring-4
    scan_k<<<dim3(H_N * 4), 64, 0, stream>>>(pk, souts);

    // 9) residual + cast + v_first passthrough
    resid_k<<<dim3(T_LEN * H_N), 64, 0, stream>>>(rbuf, kbuf, vbuf, souts, r_k, vfirst,
                                                  ob, dout);

    // 10) final GEMM: dout[0:BTC] = ob @ Wo
    gemm_lds_128<<<dim3(8, 16), 256, 0, stream>>>(ob, WoT, dout, T_LEN, C_DIM, C_DIM);
}

// Round 7
// 809.112 us; speedup vs baseline: 1.2345x; 1.1811x over previous
//
#include <hip/hip_runtime.h>
#include <math.h>

#define T_LEN 1024
#define C_DIM 2048
#define H_N   32
#define HEAD  64
#define BTC   (T_LEN * C_DIM)
#define REC   384   // packed floats per (t,h): [d 64][a 64][b 64][k 64][v 64][r 64]

typedef __attribute__((ext_vector_type(8))) __bf16 bf16x8;
typedef __attribute__((ext_vector_type(4))) float  f32x4;

// s_waitcnt immediates (gfx9: vmcnt[3:0]+[15:14], expcnt[6:4], lgkmcnt[11:8])
#define WAIT_VM6    3958   // vmcnt(6),  expcnt/lgkmcnt unconstrained
#define WAIT_LGKM0  49279  // lgkmcnt(0), vmcnt/expcnt unconstrained

// ---------------- async global->LDS helper (16B/lane, wave-uniform LDS base) -------------
__device__ __forceinline__ void gll16(const void* g, void* l) {
    __builtin_amdgcn_global_load_lds((const __attribute__((address_space(1))) void*)g,
                                     (__attribute__((address_space(3))) void*)l, 16, 0, 0);
}

// 8-lane reduce, pure DPP (VALU latency, no LDS pipe):
// xor1 (quad_perm), xor2 (quad_perm), then row_half_mirror to grab the other quad
// (valid because after the first two steps all lanes of a quad hold the quad sum).
__device__ __forceinline__ float oct_add(float x) {
    int a = __builtin_amdgcn_mov_dpp(__float_as_int(x), 0xB1, 0xF, 0xF, true);   // quad_perm [1,0,3,2]
    float y = x + __int_as_float(a);
    int b = __builtin_amdgcn_mov_dpp(__float_as_int(y), 0x4E, 0xF, 0xF, true);   // quad_perm [2,3,0,1]
    float z = y + __int_as_float(b);
    int c = __builtin_amdgcn_mov_dpp(__float_as_int(z), 0x141, 0xF, 0xF, true);  // row_half_mirror
    return z + __int_as_float(c);
}

// ---------------- elementwise cast kernels ----------------
__global__ void cast_bf16_k(const float* __restrict__ s, __bf16* __restrict__ d, int n) {
    int i = blockIdx.x * 256 + threadIdx.x;
    if (i < n) d[i] = (__bf16)s[i];
}
__global__ void tanh_cast_k(const float* __restrict__ s, __bf16* __restrict__ d, int n) {
    int i = blockIdx.x * 256 + threadIdx.x;
    if (i < n) d[i] = (__bf16)tanhf(s[i]);
}

// ---------------- transpose + cast: dst[c*R + r] = (bf16)src[r*C + c] ----------------
__global__ void transpose_cast_k(const float* __restrict__ src, __bf16* __restrict__ dst,
                                 int R, int C) {
    __shared__ float tile[32][33];
    int c0 = blockIdx.x * 32, r0 = blockIdx.y * 32;
    int tx = threadIdx.x, ty = threadIdx.y;
#pragma unroll
    for (int i = 0; i < 32; i += 8)
        tile[ty + i][tx] = src[(size_t)(r0 + ty + i) * C + c0 + tx];
    __syncthreads();
#pragma unroll
    for (int i = 0; i < 32; i += 8)
        dst[(size_t)(c0 + ty + i) * R + r0 + tx] = (__bf16)tile[tx][ty + i];
}

// ---------------- big GEMM, m97 structure: 128x128 tile, LDS-DMA staging ----------------
__global__ __launch_bounds__(256) void gemm_lds_128(
    const __bf16* __restrict__ A, const __bf16* __restrict__ BT,
    float* __restrict__ O, int M, int N, int K) {
    __shared__ __bf16 As[128 * 32];
    __shared__ __bf16 Bs[128 * 32];
    int tid  = threadIdx.x;
    int lane = tid & 63;
    int wv   = tid >> 6;
    int m    = lane & 15;
    int q    = lane >> 4;
    int wr   = wv >> 1, wc = wv & 1;
    int row0 = blockIdx.x * 128;
    int col0 = blockIdx.y * 128;

    int srow  = tid >> 2;
    int skoff = (tid & 3) * 8;
    const __bf16* agp = A  + (size_t)(row0 + srow) * K + skoff;
    const __bf16* bgp = BT + (size_t)(col0 + srow) * K + skoff;
    __bf16* alp = As + (size_t)(tid & ~63) * 8;   // wave-uniform base (+ HW lane*16B)
    __bf16* blp = Bs + (size_t)(tid & ~63) * 8;

    f32x4 acc[4][4];
#pragma unroll
    for (int i = 0; i < 4; i++)
#pragma unroll
        for (int j = 0; j < 4; j++) acc[i][j] = {0.f, 0.f, 0.f, 0.f};

    for (int k0 = 0; k0 < K; k0 += 32) {
        gll16(agp + k0, alp);
        gll16(agp + (size_t)64 * K + k0, alp + 64 * 32);
        gll16(bgp + k0, blp);
        gll16(bgp + (size_t)64 * K + k0, blp + 64 * 32);
        __syncthreads();

        bf16x8 af[4], bf[4];
#pragma unroll
        for (int i = 0; i < 4; i++)
            af[i] = *(const bf16x8*)&As[(wr * 64 + i * 16 + m) * 32 + q * 8];
#pragma unroll
        for (int j = 0; j < 4; j++)
            bf[j] = *(const bf16x8*)&Bs[(wc * 64 + j * 16 + m) * 32 + q * 8];
#pragma unroll
        for (int i = 0; i < 4; i++)
#pragma unroll
            for (int j = 0; j < 4; j++)
                acc[i][j] = __builtin_amdgcn_mfma_f32_16x16x32_bf16(af[i], bf[j], acc[i][j], 0, 0, 0);
        __syncthreads();
    }

#pragma unroll
    for (int i = 0; i < 4; i++) {
        int orow = row0 + wr * 64 + i * 16 + q * 4;
#pragma unroll
        for (int j = 0; j < 4; j++) {
            int ocol = col0 + wc * 64 + j * 16 + m;
#pragma unroll
            for (int t = 0; t < 4; t++)
                O[(size_t)(orow + t) * N + ocol] = acc[i][j][t];
        }
    }
}

// ---------------- small GEMM: one wave per 16x16 tile ----------------
__global__ __launch_bounds__(64) void gemm_bt_w16(
    const __bf16* __restrict__ A, const __bf16* __restrict__ BT,
    float* __restrict__ O, int M, int N, int K) {
    int lane = threadIdx.x & 63;
    int m = lane & 15, q = lane >> 4;
    int row0 = blockIdx.x * 16;
    int col0 = blockIdx.y * 16;
    const __bf16* ap = A  + (size_t)(row0 + m) * K + q * 8;
    const __bf16* bp = BT + (size_t)(col0 + m) * K + q * 8;
    f32x4 acc = {0.f,0.f,0.f,0.f};
    for (int k0 = 0; k0 < K; k0 += 32) {
        bf16x8 av = *(const bf16x8*)(ap + k0);
        bf16x8 bv = *(const bf16x8*)(bp + k0);
        acc = __builtin_amdgcn_mfma_f32_16x16x32_bf16(av, bv, acc, 0, 0, 0);
    }
    int orow = row0 + q * 4;
    int ocol = col0 + m;
#pragma unroll
    for (int i = 0; i < 4; i++)
        O[(size_t)(orow + i) * N + ocol] = acc[i];
}

// ---------------- prep: decay / gates / kk-normalize + mask folding + packing ----------------
__global__ __launch_bounds__(64) void prep_k(
    float* __restrict__ kbuf, float* __restrict__ vbuf,
    const float* __restrict__ vfirst, const float* __restrict__ rbuf,
    const float* __restrict__ ywb, const float* __restrict__ yab,
    const float* __restrict__ yvb,
    float* __restrict__ pk,
    const float* __restrict__ w0, const float* __restrict__ a0,
    const float* __restrict__ v0, const float* __restrict__ k_k,
    const float* __restrict__ k_a, const float* __restrict__ amask) {
    int t = blockIdx.x >> 5;
    int h = blockIdx.x & 31;
    int n = threadIdx.x;
    int cc  = h * HEAD + n;
    int idx = t * C_DIM + cc;
    float m = amask[t];

    float kv = kbuf[idx];
    float vv = vbuf[idx];
    float wv = w0[cc] + ywb[idx];
    float wfin = -log1pf(expf(-wv)) - 0.6f;       // -softplus(-x) - 0.6
    float dec  = expf(-expf(wfin));
    float sv   = 1.f / (1.f + expf(-(v0[cc] + yvb[idx])));
    float vnew = fmaf(vfirst[idx] - vv, sv, vv);
    float av   = 1.f / (1.f + expf(-(a0[cc] + yab[idx])));
    float kkp  = kv * k_k[cc];
    float ss = kkp * kkp;
#pragma unroll
    for (int off = 32; off > 0; off >>= 1) ss += __shfl_xor(ss, off);
    float kkn  = kkp / fmaxf(sqrtf(ss), 1e-12f);
    float knew = kv * (1.f + (av - 1.f) * k_a[cc]);

    size_t rec = ((size_t)t * H_N + h) * REC;
    pk[rec + n]       = dec * m + (1.f - m);   // d_eff
    pk[rec + 64 + n]  = -kkn * m;              // a_eff
    pk[rec + 128 + n] = kkn * av * m;          // b_eff
    pk[rec + 192 + n] = knew * m;              // k_eff
    pk[rec + 256 + n] = vnew * m;              // v_eff
    pk[rec + 320 + n] = rbuf[idx];             // r (unmasked)
    kbuf[idx] = knew;                          // unmasked, for residual
    vbuf[idx] = vnew;                          // unmasked, for residual
}

// ---------------- sequential scan: 256 single-wave blocks, DPP reduce, LDS-DMA ring-4 ----
// block = (head h, row-group g of 8 rows); lane = (r<<3)|c holds S[g*8+r][c*8..c*8+8).
// launch_bounds(64,1): lift VGPR cap so the per-step operand set stays in registers.
// Reduce over the 8 col-chunks = 3 DPP ops (quad xor1, xor2, half-mirror).
__global__ __launch_bounds__(64, 1) void scan_k(
    const float* __restrict__ pk, float* __restrict__ out) {
    int b = blockIdx.x;
    int xcd  = b & 7;
    int rest = b >> 3;
    int hi   = rest & 3;
    int g    = rest >> 2;          // 0..7
    int h    = xcd + 8 * hi;

    int lane = threadIdx.x;
    int r = lane >> 3;             // 0..7
    int c = lane & 7;              // 0..7
    int row = g * 8 + r;
    int jb  = c * 8;

    __shared__ float lds[4][512];  // slot: [d|a|b|k|v|r|pad128]

    float S[8];
#pragma unroll
    for (int j = 0; j < 8; j++) S[j] = 0.f;

    auto issue_slot = [&](int slot, int t) {
        const float* rec = pk + ((size_t)t * H_N + h) * REC;
        gll16(rec + lane * 4, &lds[slot][0]);          // floats [0,256): d,a,b,k
        gll16(rec + 256 + lane * 4, &lds[slot][256]);  // floats [256,512): v,r (+overread)
    };

    issue_slot(0, 0);
    issue_slot(1, 1);
    issue_slot(2, 2);
    issue_slot(3, 3);

    int off = h * HEAD;

    for (int t = 0; t < T_LEN; t++) {
        int slot = t & 3;
        __builtin_amdgcn_s_waitcnt(WAIT_VM6);    // slot's 2 DMAs retired
        const float* L = &lds[slot][0];
        float dv[8], av[8], bv[8], kv[8], rv[8];
        *(float4*)&av[0] = *(const float4*)(L + 64 + jb);
        *(float4*)&av[4] = *(const float4*)(L + 64 + jb + 4);
        *(float4*)&dv[0] = *(const float4*)(L + jb);
        *(float4*)&dv[4] = *(const float4*)(L + jb + 4);
        *(float4*)&bv[0] = *(const float4*)(L + 128 + jb);
        *(float4*)&bv[4] = *(const float4*)(L + 128 + jb + 4);
        *(float4*)&kv[0] = *(const float4*)(L + 192 + jb);
        *(float4*)&kv[4] = *(const float4*)(L + 192 + jb + 4);
        float vv = L[256 + row];
        *(float4*)&rv[0] = *(const float4*)(L + 320 + jb);
        *(float4*)&rv[4] = *(const float4*)(L + 320 + jb + 4);

        // all operands in registers -> slot reusable
        __builtin_amdgcn_s_waitcnt(WAIT_LGKM0);
        int tn = (t + 4 < T_LEN) ? t + 4 : T_LEN - 1;
        issue_slot(slot, tn);

        // sa = sum_j S[j]*a[j] over the row (8 local + 8-lane DPP reduce)
        float p0 = 0.f, p1 = 0.f;
#pragma unroll
        for (int j = 0; j < 4; j++) {
            p0 = fmaf(S[j],     av[j],     p0);
            p1 = fmaf(S[j + 4], av[j + 4], p1);
        }
        float sa = oct_add(p0 + p1);

        // state update + output dot
        float o0 = 0.f, o1 = 0.f;
#pragma unroll
        for (int j = 0; j < 4; j++) {
            float s0 = fmaf(dv[j], S[j], fmaf(sa, bv[j], vv * kv[j]));
            S[j] = s0;  o0 = fmaf(s0, rv[j], o0);
            float s1 = fmaf(dv[j + 4], S[j + 4], fmaf(sa, bv[j + 4], vv * kv[j + 4]));
            S[j + 4] = s1;  o1 = fmaf(s1, rv[j + 4], o1);
        }
        float op = oct_add(o0 + o1);
        if (c == 0) out[off + row] = op;

        off += C_DIM;
    }
}

// ---------------- residual + cast + v_first passthrough ----------------
__global__ __launch_bounds__(64) void resid_k(
    const float* __restrict__ rbuf, const float* __restrict__ kbuf,
    const float* __restrict__ vbuf, const float* __restrict__ souts,
    const float* __restrict__ r_k, const float* __restrict__ vfirst,
    __bf16* __restrict__ ob, float* __restrict__ dout) {
    int t = blockIdx.x >> 5;
    int h = blockIdx.x & 31;
    int n = threadIdx.x;
    int idx = t * C_DIM + h * HEAD + n;
    float s = rbuf[idx] * kbuf[idx] * r_k[h * HEAD + n];
#pragma unroll
    for (int off = 32; off > 0; off >>= 1) s += __shfl_xor(s, off);
    float ov = souts[idx] + s * vbuf[idx];
    ob[idx] = (__bf16)ov;
    dout[BTC + idx] = vfirst[idx];
}

// ---------------- host launcher ----------------
extern "C" void kernel_launch(void* const* d_in, const int* in_sizes, int n_in,
                              void* d_out, int out_size, void* d_ws, size_t ws_size,
                              hipStream_t stream) {
    const float* x      = (const float*)d_in[0];
    const float* vfirst = (const float*)d_in[1];
    const float* amask  = (const float*)d_in[2];
    const float* w0 = (const float*)d_in[3];
    const float* w1 = (const float*)d_in[4];
    const float* w2 = (const float*)d_in[5];
    const float* a0 = (const float*)d_in[6];
    const float* a1 = (const float*)d_in[7];
    const float* a2 = (const float*)d_in[8];
    const float* v0 = (const float*)d_in[9];
    const float* v1 = (const float*)d_in[10];
    const float* v2 = (const float*)d_in[11];
    const float* k_k = (const float*)d_in[12];
    const float* k_a = (const float*)d_in[13];
    const float* r_k = (const float*)d_in[14];
    const float* Wr = (const float*)d_in[15];
    const float* Wk = (const float*)d_in[16];
    const float* Wv = (const float*)d_in[17];
    const float* Wo = (const float*)d_in[18];
    float* dout = (float*)d_out;

    char* wp = (char*)d_ws;
    auto alloc = [&](size_t bytes) -> void* {
        void* p = (void*)wp;
        wp += (bytes + 255) & ~(size_t)255;
        return p;
    };
    __bf16* xb  = (__bf16*)alloc((size_t)BTC * 2);
    __bf16* WrT = (__bf16*)alloc((size_t)C_DIM * C_DIM * 2);
    __bf16* WkT = (__bf16*)alloc((size_t)C_DIM * C_DIM * 2);
    __bf16* WvT = (__bf16*)alloc((size_t)C_DIM * C_DIM * 2);
    __bf16* WoT = (__bf16*)alloc((size_t)C_DIM * C_DIM * 2);
    __bf16* w1T = (__bf16*)alloc((size_t)96 * C_DIM * 2);
    __bf16* a1T = (__bf16*)alloc((size_t)96 * C_DIM * 2);
    __bf16* v1T = (__bf16*)alloc((size_t)64 * C_DIM * 2);
    __bf16* w2T = (__bf16*)alloc((size_t)C_DIM * 96 * 2);
    __bf16* a2T = (__bf16*)alloc((size_t)C_DIM * 96 * 2);
    __bf16* v2T = (__bf16*)alloc((size_t)C_DIM * 64 * 2);
    float*  rbuf = (float*)alloc((size_t)BTC * 4);
    float*  kbuf = (float*)alloc((size_t)BTC * 4);
    float*  vbuf = (float*)alloc((size_t)BTC * 4);
    float*  hw  = (float*)alloc((size_t)T_LEN * 96 * 4);
    float*  ha  = (float*)alloc((size_t)T_LEN * 96 * 4);
    float*  hv  = (float*)alloc((size_t)T_LEN * 64 * 4);
    __bf16* hwb = (__bf16*)alloc((size_t)T_LEN * 96 * 2);
    __bf16* hab = (__bf16*)alloc((size_t)T_LEN * 96 * 2);
    __bf16* hvb = (__bf16*)alloc((size_t)T_LEN * 64 * 2);
    float*  ywb = (float*)alloc((size_t)BTC * 4);   // LoRA w output
    float*  yab = (float*)alloc((size_t)BTC * 4);   // LoRA a output
    float*  yvb = (float*)alloc((size_t)BTC * 4);   // LoRA v output
    float*  pk  = (float*)alloc((size_t)T_LEN * H_N * REC * 4 + 4096);
    float*  souts = (float*)alloc((size_t)BTC * 4);
    __bf16* ob  = (__bf16*)alloc((size_t)BTC * 2);

    // 1) cast x -> bf16
    cast_bf16_k<<<dim3(BTC / 256), 256, 0, stream>>>(x, xb, BTC);

    // 2) transpose+cast all weights (dst = C x R)
    dim3 tb(32, 8);
    transpose_cast_k<<<dim3(64, 64), tb, 0, stream>>>(Wr, WrT, C_DIM, C_DIM);
    transpose_cast_k<<<dim3(64, 64), tb, 0, stream>>>(Wk, WkT, C_DIM, C_DIM);
    transpose_cast_k<<<dim3(64, 64), tb, 0, stream>>>(Wv, WvT, C_DIM, C_DIM);
    transpose_cast_k<<<dim3(64, 64), tb, 0, stream>>>(Wo, WoT, C_DIM, C_DIM);
    transpose_cast_k<<<dim3(3, 64), tb, 0, stream>>>(w1, w1T, C_DIM, 96);
    transpose_cast_k<<<dim3(3, 64), tb, 0, stream>>>(a1, a1T, C_DIM, 96);
    transpose_cast_k<<<dim3(2, 64), tb, 0, stream>>>(v1, v1T, C_DIM, 64);
    transpose_cast_k<<<dim3(64, 3), tb, 0, stream>>>(w2, w2T, 96, C_DIM);
    transpose_cast_k<<<dim3(64, 3), tb, 0, stream>>>(a2, a2T, 96, C_DIM);
    transpose_cast_k<<<dim3(64, 2), tb, 0, stream>>>(v2, v2T, 64, C_DIM);

    // 3) big GEMMs: r, k, v (m97-style LDS-staged)
    gemm_lds_128<<<dim3(8, 16), 256, 0, stream>>>(xb, WrT, rbuf, T_LEN, C_DIM, C_DIM);
    gemm_lds_128<<<dim3(8, 16), 256, 0, stream>>>(xb, WkT, kbuf, T_LEN, C_DIM, C_DIM);
    gemm_lds_128<<<dim3(8, 16), 256, 0, stream>>>(xb, WvT, vbuf, T_LEN, C_DIM, C_DIM);

    // 4) LoRA first stage
    gemm_bt_w16<<<dim3(64, 6), 64, 0, stream>>>(xb, w1T, hw, T_LEN, 96, C_DIM);
    gemm_bt_w16<<<dim3(64, 6), 64, 0, stream>>>(xb, a1T, ha, T_LEN, 96, C_DIM);
    gemm_bt_w16<<<dim3(64, 4), 64, 0, stream>>>(xb, v1T, hv, T_LEN, 64, C_DIM);

    // 5) activations + cast
    tanh_cast_k<<<dim3((T_LEN * 96 + 255) / 256), 256, 0, stream>>>(hw, hwb, T_LEN * 96);
    cast_bf16_k<<<dim3((T_LEN * 96 + 255) / 256), 256, 0, stream>>>(ha, hab, T_LEN * 96);
    cast_bf16_k<<<dim3((T_LEN * 64 + 255) / 256), 256, 0, stream>>>(hv, hvb, T_LEN * 64);

    // 6) LoRA second stage (LDS-staged 128-tile; K=96 -> 3 iters)
    gemm_lds_128<<<dim3(8, 16), 256, 0, stream>>>(hwb, w2T, ywb, T_LEN, C_DIM, 96);
    gemm_lds_128<<<dim3(8, 16), 256, 0, stream>>>(hab, a2T, yab, T_LEN, C_DIM, 96);
    gemm_lds_128<<<dim3(8, 16), 256, 0, stream>>>(hvb, v2T, yvb, T_LEN, C_DIM, 64);

    // 7) prep: decay, gates, kk-normalize, mask folding, record packing
    prep_k<<<dim3(T_LEN * H_N), 64, 0, stream>>>(kbuf, vbuf, vfirst, rbuf, ywb, yab, yvb,
                                                 pk, w0, a0, v0, k_k, k_a, amask);

    // 8) sequential scan: 256 blocks x 1 wave, DPP oct-reduce, LDS-DMA ring-4
    scan_k<<<dim3(H_N * 8), 64, 0, stream>>>(pk, souts);

    // 9) residual + cast + v_first passthrough
    resid_k<<<dim3(T_LEN * H_N), 64, 0, stream>>>(rbuf, kbuf, vbuf, souts, r_k, vfirst,
                                                  ob, dout);

    // 10) final GEMM: dout[0:BTC] = ob @ Wo
    gemm_lds_128<<<dim3(8, 16), 256, 0, stream>>>(ob, WoT, dout, T_LEN, C_DIM, C_DIM);
}

// Round 8
// 709.632 us; speedup vs baseline: 1.4075x; 1.1402x over previous
//
#include <hip/hip_runtime.h>
#include <math.h>

#define T_LEN 1024
#define C_DIM 2048
#define H_N   32
#define HEAD  64
#define BTC   (T_LEN * C_DIM)
#define REC   384   // packed floats per (t,h): [d 64][a 64][b 64][k 64][v 64][r 64]
#define RKV_N 6144  // fused r|k|v GEMM output width

typedef __attribute__((ext_vector_type(8))) __bf16 bf16x8;
typedef __attribute__((ext_vector_type(4))) float  f32x4;

// s_waitcnt immediates (gfx9: vmcnt[3:0] bits3:0, vmcnt[5:4] bits15:14, expcnt 6:4, lgkmcnt 11:8)
#define WAIT_VM6    3958   // vmcnt(6)
#define WAIT_VM7    3959   // vmcnt(7)
#define WAIT_VM8    3960   // vmcnt(8)
#define WAIT_VM9    3961   // vmcnt(9)
#define WAIT_VM10   3962   // vmcnt(10)
#define WAIT_LGKM0  49279  // lgkmcnt(0)

// ---------------- async global->LDS helper (16B/lane, wave-uniform LDS base) -------------
__device__ __forceinline__ void gll16(const void* g, void* l) {
    __builtin_amdgcn_global_load_lds((const __attribute__((address_space(1))) void*)g,
                                     (__attribute__((address_space(3))) void*)l, 16, 0, 0);
}

// 16-lane reduce, pure DPP: quad xor1, quad xor2, row_half_mirror (8), row_mirror (16)
__device__ __forceinline__ float hex_add(float x) {
    int a = __builtin_amdgcn_mov_dpp(__float_as_int(x), 0xB1, 0xF, 0xF, true);   // quad_perm [1,0,3,2]
    float y = x + __int_as_float(a);
    int b = __builtin_amdgcn_mov_dpp(__float_as_int(y), 0x4E, 0xF, 0xF, true);   // quad_perm [2,3,0,1]
    float z = y + __int_as_float(b);
    int c = __builtin_amdgcn_mov_dpp(__float_as_int(z), 0x141, 0xF, 0xF, true);  // row_half_mirror
    float w = z + __int_as_float(c);
    int d = __builtin_amdgcn_mov_dpp(__float_as_int(w), 0x140, 0xF, 0xF, true);  // row_mirror
    return w + __int_as_float(d);
}

// ---------------- elementwise cast kernels ----------------
__global__ void cast_bf16_k(const float* __restrict__ s, __bf16* __restrict__ d, int n) {
    int i = blockIdx.x * 256 + threadIdx.x;
    if (i < n) d[i] = (__bf16)s[i];
}
__global__ void tanh_cast_k(const float* __restrict__ s, __bf16* __restrict__ d, int n) {
    int i = blockIdx.x * 256 + threadIdx.x;
    if (i < n) d[i] = (__bf16)tanhf(s[i]);
}

// ---------------- transpose + cast: dst[c*R + r] = (bf16)src[r*C + c] ----------------
__global__ void transpose_cast_k(const float* __restrict__ src, __bf16* __restrict__ dst,
                                 int R, int C) {
    __shared__ float tile[32][33];
    int c0 = blockIdx.x * 32, r0 = blockIdx.y * 32;
    int tx = threadIdx.x, ty = threadIdx.y;
#pragma unroll
    for (int i = 0; i < 32; i += 8)
        tile[ty + i][tx] = src[(size_t)(r0 + ty + i) * C + c0 + tx];
    __syncthreads();
#pragma unroll
    for (int i = 0; i < 32; i += 8)
        dst[(size_t)(c0 + ty + i) * R + r0 + tx] = (__bf16)tile[tx][ty + i];
}

// ---------------- GEMM 64x128 tile, LDS-DMA staging: O = A(MxK) * BT(NxK) ----------------
// block 256 = 4 waves; wave computes 32x64 (2x4 MFMA tiles). 3 DMA + 8 MFMA + 6 ds_read/iter.
__global__ __launch_bounds__(256) void gemm_lds_64x128(
    const __bf16* __restrict__ A, const __bf16* __restrict__ BT,
    float* __restrict__ O, int M, int N, int K) {
    __shared__ __bf16 As[64 * 32];
    __shared__ __bf16 Bs[128 * 32];
    int tid  = threadIdx.x;
    int lane = tid & 63;
    int wv   = tid >> 6;
    int m    = lane & 15;
    int q    = lane >> 4;
    int wr   = wv >> 1, wc = wv & 1;
    int row0 = blockIdx.x * 64;
    int col0 = blockIdx.y * 128;

    int srow  = tid >> 2;          // 0..63
    int skoff = (tid & 3) * 8;
    const __bf16* agp = A  + (size_t)(row0 + srow) * K + skoff;
    const __bf16* bgp = BT + (size_t)(col0 + srow) * K + skoff;
    __bf16* alp = As + (size_t)(tid & ~63) * 8;   // wave-uniform base (+ HW lane*16B)
    __bf16* blp = Bs + (size_t)(tid & ~63) * 8;

    f32x4 acc[2][4];
#pragma unroll
    for (int i = 0; i < 2; i++)
#pragma unroll
        for (int j = 0; j < 4; j++) acc[i][j] = {0.f, 0.f, 0.f, 0.f};

    for (int k0 = 0; k0 < K; k0 += 32) {
        gll16(agp + k0, alp);
        gll16(bgp + k0, blp);
        gll16(bgp + (size_t)64 * K + k0, blp + 64 * 32);
        __syncthreads();

        bf16x8 af[2], bfv[4];
#pragma unroll
        for (int i = 0; i < 2; i++)
            af[i] = *(const bf16x8*)&As[(wr * 32 + i * 16 + m) * 32 + q * 8];
#pragma unroll
        for (int j = 0; j < 4; j++)
            bfv[j] = *(const bf16x8*)&Bs[(wc * 64 + j * 16 + m) * 32 + q * 8];
#pragma unroll
        for (int i = 0; i < 2; i++)
#pragma unroll
            for (int j = 0; j < 4; j++)
                acc[i][j] = __builtin_amdgcn_mfma_f32_16x16x32_bf16(af[i], bfv[j], acc[i][j], 0, 0, 0);
        __syncthreads();
    }

#pragma unroll
    for (int i = 0; i < 2; i++) {
        int orow = row0 + wr * 32 + i * 16 + q * 4;
#pragma unroll
        for (int j = 0; j < 4; j++) {
            int ocol = col0 + wc * 64 + j * 16 + m;
#pragma unroll
            for (int t = 0; t < 4; t++)
                O[(size_t)(orow + t) * N + ocol] = acc[i][j][t];
        }
    }
}

// ---------------- small GEMM: one wave per 16x16 tile (LoRA stage 1) ----------------
__global__ __launch_bounds__(64) void gemm_bt_w16(
    const __bf16* __restrict__ A, const __bf16* __restrict__ BT,
    float* __restrict__ O, int M, int N, int K) {
    int lane = threadIdx.x & 63;
    int m = lane & 15, q = lane >> 4;
    int row0 = blockIdx.x * 16;
    int col0 = blockIdx.y * 16;
    const __bf16* ap = A  + (size_t)(row0 + m) * K + q * 8;
    const __bf16* bp = BT + (size_t)(col0 + m) * K + q * 8;
    f32x4 acc = {0.f,0.f,0.f,0.f};
    for (int k0 = 0; k0 < K; k0 += 32) {
        bf16x8 av = *(const bf16x8*)(ap + k0);
        bf16x8 bv = *(const bf16x8*)(bp + k0);
        acc = __builtin_amdgcn_mfma_f32_16x16x32_bf16(av, bv, acc, 0, 0, 0);
    }
    int orow = row0 + q * 4;
    int ocol = col0 + m;
#pragma unroll
    for (int i = 0; i < 4; i++)
        O[(size_t)(orow + i) * N + ocol] = acc[i];
}

// ---------------- prep: decay / gates / kk-normalize + mask folding + packing ----------------
// rkv layout: [t][0:2048)=r, [2048:4096)=k, [4096:6144)=v (stride RKV_N)
__global__ __launch_bounds__(64) void prep_k(
    float* __restrict__ rkv,
    const float* __restrict__ vfirst,
    const float* __restrict__ ywb, const float* __restrict__ yab,
    const float* __restrict__ yvb,
    float* __restrict__ pk,
    const float* __restrict__ w0, const float* __restrict__ a0,
    const float* __restrict__ v0, const float* __restrict__ k_k,
    const float* __restrict__ k_a, const float* __restrict__ amask) {
    int t = blockIdx.x >> 5;
    int h = blockIdx.x & 31;
    int n = threadIdx.x;
    int cc   = h * HEAD + n;
    int idx  = t * C_DIM + cc;          // for ywb/yab/yvb/vfirst
    size_t idx6 = (size_t)t * RKV_N + cc;
    float m = amask[t];

    float rr = rkv[idx6];
    float kv = rkv[idx6 + 2048];
    float vv = rkv[idx6 + 4096];
    float wv = w0[cc] + ywb[idx];
    float wfin = -log1pf(expf(-wv)) - 0.6f;       // -softplus(-x) - 0.6
    float dec  = expf(-expf(wfin));
    float sv   = 1.f / (1.f + expf(-(v0[cc] + yvb[idx])));
    float vnew = fmaf(vfirst[idx] - vv, sv, vv);
    float av   = 1.f / (1.f + expf(-(a0[cc] + yab[idx])));
    float kkp  = kv * k_k[cc];
    float ss = kkp * kkp;
#pragma unroll
    for (int off = 32; off > 0; off >>= 1) ss += __shfl_xor(ss, off);
    float kkn  = kkp / fmaxf(sqrtf(ss), 1e-12f);
    float knew = kv * (1.f + (av - 1.f) * k_a[cc]);

    size_t rec = ((size_t)t * H_N + h) * REC;
    pk[rec + n]       = dec * m + (1.f - m);   // d_eff
    pk[rec + 64 + n]  = -kkn * m;              // a_eff
    pk[rec + 128 + n] = kkn * av * m;          // b_eff
    pk[rec + 192 + n] = knew * m;              // k_eff
    pk[rec + 256 + n] = vnew * m;              // v_eff
    pk[rec + 320 + n] = rr;                    // r (unmasked)
    rkv[idx6 + 2048] = knew;                   // unmasked, for residual
    rkv[idx6 + 4096] = vnew;                   // unmasked, for residual
}

// ---------------- sequential scan: 512 single-wave blocks, DPP hex-reduce, LDS-DMA ring-4 ----
// block = (head h, row-quarter g of 4 rows); lane = r*16+c holds S[g*4+r][c*4..c*4+4).
// 512 blocks -> 2 waves/CU so one wave's stalls hide behind the other.
// vmcnt discipline: steady queue at the wait = 13 ops [store(t-4), slot t (2), ...];
// vmcnt(10) retires exactly the oldest [store, slot-DMA pair]. Prologue peeled with 6/7/8/9.
__global__ __launch_bounds__(64, 1) void scan_k(
    const float* __restrict__ pk, float* __restrict__ out) {
    int b = blockIdx.x;
    int xcd  = b & 7;
    int rest = b >> 3;       // 0..63
    int hi   = rest & 3;
    int g    = rest >> 2;    // 0..15
    int h    = xcd + 8 * hi;

    int lane = threadIdx.x;
    int r = lane >> 4;       // 0..3
    int c = lane & 15;       // 0..15
    int row = g * 4 + r;
    int jb  = c * 4;

    __shared__ float lds[4][512];  // slot: [d|a|b|k|v|r|pad128]

    float S[4] = {0.f, 0.f, 0.f, 0.f};

    auto issue_slot = [&](int slot, int t) {
        const float* rec = pk + ((size_t)t * H_N + h) * REC;
        gll16(rec + lane * 4, &lds[slot][0]);          // floats [0,256): d,a,b,k
        gll16(rec + 256 + lane * 4, &lds[slot][256]);  // floats [256,512): v,r (+overread)
    };

    issue_slot(0, 0);
    issue_slot(1, 1);
    issue_slot(2, 2);
    issue_slot(3, 3);

    int off = h * HEAD;

#define SCAN_STEP(WIMM, TT) do {                                              \
    int slot = (TT) & 3;                                                      \
    __builtin_amdgcn_s_waitcnt(WIMM);                                         \
    const float* L = &lds[slot][0];                                           \
    float4 dv = *(const float4*)(L + jb);                                     \
    float4 av = *(const float4*)(L + 64 + jb);                                \
    float4 bv = *(const float4*)(L + 128 + jb);                               \
    float4 kv = *(const float4*)(L + 192 + jb);                               \
    float  vv = L[256 + row];                                                 \
    float4 rv = *(const float4*)(L + 320 + jb);                               \
    __builtin_amdgcn_s_waitcnt(WAIT_LGKM0);                                   \
    int tn = ((TT) + 4 < T_LEN) ? (TT) + 4 : T_LEN - 1;                       \
    issue_slot(slot, tn);                                                     \
    float p0 = fmaf(S[0], av.x, S[1] * av.y);                                 \
    float p1 = fmaf(S[2], av.z, S[3] * av.w);                                 \
    float sa = hex_add(p0 + p1);                                              \
    float s0 = fmaf(dv.x, S[0], fmaf(sa, bv.x, vv * kv.x));                   \
    float s1 = fmaf(dv.y, S[1], fmaf(sa, bv.y, vv * kv.y));                   \
    float s2 = fmaf(dv.z, S[2], fmaf(sa, bv.z, vv * kv.z));                   \
    float s3 = fmaf(dv.w, S[3], fmaf(sa, bv.w, vv * kv.w));                   \
    S[0] = s0; S[1] = s1; S[2] = s2; S[3] = s3;                               \
    float o0 = fmaf(s0, rv.x, s1 * rv.y);                                     \
    float o1 = fmaf(s2, rv.z, s3 * rv.w);                                     \
    float op = hex_add(o0 + o1);                                              \
    if (c == 0) out[off + row] = op;                                          \
    off += C_DIM;                                                             \
} while (0)

    SCAN_STEP(WAIT_VM6, 0);
    SCAN_STEP(WAIT_VM7, 1);
    SCAN_STEP(WAIT_VM8, 2);
    SCAN_STEP(WAIT_VM9, 3);
    for (int t = 4; t < T_LEN; t++)
        SCAN_STEP(WAIT_VM10, t);
#undef SCAN_STEP
}

// ---------------- residual + cast + v_first passthrough ----------------
__global__ __launch_bounds__(64) void resid_k(
    const float* __restrict__ rkv, const float* __restrict__ souts,
    const float* __restrict__ r_k, const float* __restrict__ vfirst,
    __bf16* __restrict__ ob, float* __restrict__ dout) {
    int t = blockIdx.x >> 5;
    int h = blockIdx.x & 31;
    int n = threadIdx.x;
    int cc  = h * HEAD + n;
    int idx = t * C_DIM + cc;
    size_t idx6 = (size_t)t * RKV_N + cc;
    float s = rkv[idx6] * rkv[idx6 + 2048] * r_k[cc];
#pragma unroll
    for (int off = 32; off > 0; off >>= 1) s += __shfl_xor(s, off);
    float ov = souts[idx] + s * rkv[idx6 + 4096];
    ob[idx] = (__bf16)ov;
    dout[BTC + idx] = vfirst[idx];
}

// ---------------- host launcher ----------------
extern "C" void kernel_launch(void* const* d_in, const int* in_sizes, int n_in,
                              void* d_out, int out_size, void* d_ws, size_t ws_size,
                              hipStream_t stream) {
    const float* x      = (const float*)d_in[0];
    const float* vfirst = (const float*)d_in[1];
    const float* amask  = (const float*)d_in[2];
    const float* w0 = (const float*)d_in[3];
    const float* w1 = (const float*)d_in[4];
    const float* w2 = (const float*)d_in[5];
    const float* a0 = (const float*)d_in[6];
    const float* a1 = (const float*)d_in[7];
    const float* a2 = (const float*)d_in[8];
    const float* v0 = (const float*)d_in[9];
    const float* v1 = (const float*)d_in[10];
    const float* v2 = (const float*)d_in[11];
    const float* k_k = (const float*)d_in[12];
    const float* k_a = (const float*)d_in[13];
    const float* r_k = (const float*)d_in[14];
    const float* Wr = (const float*)d_in[15];
    const float* Wk = (const float*)d_in[16];
    const float* Wv = (const float*)d_in[17];
    const float* Wo = (const float*)d_in[18];
    float* dout = (float*)d_out;

    char* wp = (char*)d_ws;
    auto alloc = [&](size_t bytes) -> void* {
        void* p = (void*)wp;
        wp += (bytes + 255) & ~(size_t)255;
        return p;
    };
    __bf16* xb   = (__bf16*)alloc((size_t)BTC * 2);
    __bf16* rkvT = (__bf16*)alloc((size_t)3 * C_DIM * C_DIM * 2);  // WrT|WkT|WvT contiguous
    __bf16* WoT  = (__bf16*)alloc((size_t)C_DIM * C_DIM * 2);
    __bf16* w1T = (__bf16*)alloc((size_t)96 * C_DIM * 2);
    __bf16* a1T = (__bf16*)alloc((size_t)96 * C_DIM * 2);
    __bf16* v1T = (__bf16*)alloc((size_t)64 * C_DIM * 2);
    __bf16* w2T = (__bf16*)alloc((size_t)C_DIM * 96 * 2);
    __bf16* a2T = (__bf16*)alloc((size_t)C_DIM * 96 * 2);
    __bf16* v2T = (__bf16*)alloc((size_t)C_DIM * 64 * 2);
    float*  rkv = (float*)alloc((size_t)T_LEN * RKV_N * 4);        // fused r|k|v output
    float*  hw  = (float*)alloc((size_t)T_LEN * 96 * 4);
    float*  ha  = (float*)alloc((size_t)T_LEN * 96 * 4);
    float*  hv  = (float*)alloc((size_t)T_LEN * 64 * 4);
    __bf16* hwb = (__bf16*)alloc((size_t)T_LEN * 96 * 2);
    __bf16* hab = (__bf16*)alloc((size_t)T_LEN * 96 * 2);
    __bf16* hvb = (__bf16*)alloc((size_t)T_LEN * 64 * 2);
    float*  ywb = (float*)alloc((size_t)BTC * 4);   // LoRA w output
    float*  yab = (float*)alloc((size_t)BTC * 4);   // LoRA a output
    float*  yvb = (float*)alloc((size_t)BTC * 4);   // LoRA v output
    float*  pk  = (float*)alloc((size_t)T_LEN * H_N * REC * 4 + 4096);
    float*  souts = (float*)alloc((size_t)BTC * 4);
    __bf16* ob  = (__bf16*)alloc((size_t)BTC * 2);

    // 1) cast x -> bf16
    cast_bf16_k<<<dim3(BTC / 256), 256, 0, stream>>>(x, xb, BTC);

    // 2) transpose+cast all weights (dst = C x R); Wr/Wk/Wv into one contiguous BT
    dim3 tb(32, 8);
    transpose_cast_k<<<dim3(64, 64), tb, 0, stream>>>(Wr, rkvT, C_DIM, C_DIM);
    transpose_cast_k<<<dim3(64, 64), tb, 0, stream>>>(Wk, rkvT + (size_t)C_DIM * C_DIM, C_DIM, C_DIM);
    transpose_cast_k<<<dim3(64, 64), tb, 0, stream>>>(Wv, rkvT + (size_t)2 * C_DIM * C_DIM, C_DIM, C_DIM);
    transpose_cast_k<<<dim3(64, 64), tb, 0, stream>>>(Wo, WoT, C_DIM, C_DIM);
    transpose_cast_k<<<dim3(3, 64), tb, 0, stream>>>(w1, w1T, C_DIM, 96);
    transpose_cast_k<<<dim3(3, 64), tb, 0, stream>>>(a1, a1T, C_DIM, 96);
    transpose_cast_k<<<dim3(2, 64), tb, 0, stream>>>(v1, v1T, C_DIM, 64);
    transpose_cast_k<<<dim3(64, 3), tb, 0, stream>>>(w2, w2T, 96, C_DIM);
    transpose_cast_k<<<dim3(64, 3), tb, 0, stream>>>(a2, a2T, 96, C_DIM);
    transpose_cast_k<<<dim3(64, 2), tb, 0, stream>>>(v2, v2T, 64, C_DIM);

    // 3) fused big GEMM: rkv = xb @ [Wr|Wk|Wv]  (768 blocks = 3/CU)
    gemm_lds_64x128<<<dim3(16, 48), 256, 0, stream>>>(xb, rkvT, rkv, T_LEN, RKV_N, C_DIM);

    // 4) LoRA first stage
    gemm_bt_w16<<<dim3(64, 6), 64, 0, stream>>>(xb, w1T, hw, T_LEN, 96, C_DIM);
    gemm_bt_w16<<<dim3(64, 6), 64, 0, stream>>>(xb, a1T, ha, T_LEN, 96, C_DIM);
    gemm_bt_w16<<<dim3(64, 4), 64, 0, stream>>>(xb, v1T, hv, T_LEN, 64, C_DIM);

    // 5) activations + cast
    tanh_cast_k<<<dim3((T_LEN * 96 + 255) / 256), 256, 0, stream>>>(hw, hwb, T_LEN * 96);
    cast_bf16_k<<<dim3((T_LEN * 96 + 255) / 256), 256, 0, stream>>>(ha, hab, T_LEN * 96);
    cast_bf16_k<<<dim3((T_LEN * 64 + 255) / 256), 256, 0, stream>>>(hv, hvb, T_LEN * 64);

    // 6) LoRA second stage (64x128 tiles, 256 blocks)
    gemm_lds_64x128<<<dim3(16, 16), 256, 0, stream>>>(hwb, w2T, ywb, T_LEN, C_DIM, 96);
    gemm_lds_64x128<<<dim3(16, 16), 256, 0, stream>>>(hab, a2T, yab, T_LEN, C_DIM, 96);
    gemm_lds_64x128<<<dim3(16, 16), 256, 0, stream>>>(hvb, v2T, yvb, T_LEN, C_DIM, 64);

    // 7) prep: decay, gates, kk-normalize, mask folding, record packing
    prep_k<<<dim3(T_LEN * H_N), 64, 0, stream>>>(rkv, vfirst, ywb, yab, yvb,
                                                 pk, w0, a0, v0, k_k, k_a, amask);

    // 8) sequential scan: 512 blocks x 1 wave (2/CU), DPP hex-reduce, LDS-DMA ring-4
    scan_k<<<dim3(H_N * 16), 64, 0, stream>>>(pk, souts);

    // 9) residual + cast + v_first passthrough
    resid_k<<<dim3(T_LEN * H_N), 64, 0, stream>>>(rkv, souts, r_k, vfirst, ob, dout);

    // 10) final GEMM: dout[0:BTC] = ob @ Wo
    gemm_lds_64x128<<<dim3(16, 16), 256, 0, stream>>>(ob, WoT, dout, T_LEN, C_DIM, C_DIM);
}